// Round 9
// baseline (420.665 us; speedup 1.0000x reference)
//
#include <hip/hip_runtime.h>

// ---------------------------------------------------------------------------
// ChemConv — MEASUREMENT ROUND: K2 launched 4x (idempotent, bit-identical
// partials) so T(K2) = (dur_us - 318)/3. Everything else identical to R7.
//
//   out[a,o] = sum_{n,f} conn[a,n,f] * W[n*12+f, o] + sum_{f,c} bond[a,f,c]*bf[o,f,c+1]
//   W[n*12+f, o] = bf[o,f,0] * sum_i pf[o,f,i] * x[n,i]
//
// K2 = M2048 x N64 x K24576 GEMM, conn read ONCE (201 MB -> ~32us floor).
// f32 accuracy via hi/lo bf16 split, 3 MFMA products (hh+hl+lh), err ~2^-18.
// ws: [WT_hi 3MB][WT_lo 3MB][partials 16MB] = 23,068,672 B
// ---------------------------------------------------------------------------

#define NATOM 2048
#define IN_D 64
#define OUT_D 64
#define FLEN 12
#define KTOT (NATOM * FLEN)        // 24576
#define KSPLIT 32
#define KCHUNK (KTOT / KSPLIT)     // 768
#define BM 64
#define KS 64
#define NITER (KCHUNK / KS)        // 12

typedef __attribute__((ext_vector_type(8))) short short8;   // MFMA bf16 A/B frag
typedef __attribute__((ext_vector_type(4))) float f32x4;    // MFMA C/D frag
typedef __attribute__((ext_vector_type(4))) unsigned short u16x4;

// RNE f32 -> bf16 hi/lo split: x ~= hi + lo, |x-hi-lo| <~ 2^-18 |x|
__device__ __forceinline__ void split2(float x, short& h, short& l) {
    unsigned u = __builtin_bit_cast(unsigned, x);
    unsigned r = u + 0x7fffu + ((u >> 16) & 1u);
    h = (short)(r >> 16);
    float hf = __builtin_bit_cast(float, r & 0xffff0000u);
    float res = x - hf;                       // exact (Sterbenz)
    unsigned u2 = __builtin_bit_cast(unsigned, res);
    l = (short)((u2 + 0x7fffu + ((u2 >> 16) & 1u)) >> 16);
}

// async global->LDS, 16B per lane. LDS dest must be wave-uniform base
// (HW adds lane*16); global src is per-lane.
__device__ __forceinline__ void gll16(const void* g, void* l) {
    __builtin_amdgcn_global_load_lds(
        (__attribute__((address_space(1))) void*)g,
        (__attribute__((address_space(3))) void*)l, 16, 0, 0);
}

// ---------------------------------------------------------------------------
// K1: W[o][k=n*12+f] = bf[o,f,0] * sum_i pf[o,f,i]*x[n,i], stored hi/lo bf16
// o-major. grid 512 = 16 o-blocks x 32 n-blocks; 256 thr.
// ---------------------------------------------------------------------------
__global__ __launch_bounds__(256) void compute_w_kernel(
    const float* __restrict__ x,        // [2048][64]
    const float* __restrict__ pf,       // [64][12][64]
    const float* __restrict__ bf,       // [64][12][3]
    unsigned short* __restrict__ wt_hi, // [64][24576]
    unsigned short* __restrict__ wt_lo)
{
    __shared__ float x_lds[64][66];
    const int t = threadIdx.x;
    const int ob = blockIdx.x & 15;
    const int nb = blockIdx.x >> 4;

    {
        const int r = t >> 2;
        const int i0 = (t & 3) * 16;
        const float* src = x + (nb * 64 + r) * IN_D + i0;
        #pragma unroll
        for (int j = 0; j < 4; ++j) {
            float4 v = *(const float4*)(src + 4 * j);
            x_lds[r][i0 + 4 * j + 0] = v.x;
            x_lds[r][i0 + 4 * j + 1] = v.y;
            x_lds[r][i0 + 4 * j + 2] = v.z;
            x_lds[r][i0 + 4 * j + 3] = v.w;
        }
    }
    __syncthreads();

    const int l = t & 63;
    const int o = ob * 4 + (t >> 6);    // wave-uniform -> broadcast loads
    const int n = nb * 64 + l;

    float acc[FLEN];
    #pragma unroll
    for (int f = 0; f < FLEN; ++f) acc[f] = 0.f;

    for (int i = 0; i < IN_D; i += 4) {
        float x0 = x_lds[l][i + 0], x1 = x_lds[l][i + 1];
        float x2 = x_lds[l][i + 2], x3 = x_lds[l][i + 3];
        #pragma unroll
        for (int f = 0; f < FLEN; ++f) {
            float4 p = *(const float4*)(pf + (o * FLEN + f) * IN_D + i);
            acc[f] += p.x * x0 + p.y * x1 + p.z * x2 + p.w * x3;
        }
    }

    short hi[FLEN], lo[FLEN];
    #pragma unroll
    for (int f = 0; f < FLEN; ++f) {
        float wv = acc[f] * bf[(o * FLEN + f) * 3 + 0];
        split2(wv, hi[f], lo[f]);
    }
    unsigned short* dh = wt_hi + o * KTOT + n * FLEN;
    unsigned short* dl = wt_lo + o * KTOT + n * FLEN;
    #pragma unroll
    for (int q = 0; q < 3; ++q) {
        u16x4 vh = { (unsigned short)hi[4*q], (unsigned short)hi[4*q+1],
                     (unsigned short)hi[4*q+2], (unsigned short)hi[4*q+3] };
        u16x4 vl = { (unsigned short)lo[4*q], (unsigned short)lo[4*q+1],
                     (unsigned short)lo[4*q+2], (unsigned short)lo[4*q+3] };
        *(u16x4*)(dh + 4 * q) = vh;
        *(u16x4*)(dl + 4 * q) = vl;
    }
}

// ---------------------------------------------------------------------------
// K2: main GEMM. grid 1024 (XCD-swizzled) = 32 mblk x 32 kblk; 256 thr, 4 waves.
// LDS 32KB: A f32 [64 rows][16 chunks of 16B]; LDS chunk cc of row R holds
// global chunk cc^(R&15). B hi/lo ushort [64 o][8 chunks of 16B], key o&7.
// All staging via global_load_lds; hi/lo split at fragment-load time.
// ---------------------------------------------------------------------------
__global__ __launch_bounds__(256, 4) void main_gemm_kernel(
    const float* __restrict__ conn,     // [2048][24576]
    const unsigned short* __restrict__ wt_hi,
    const unsigned short* __restrict__ wt_lo,
    float* __restrict__ partials)       // [KSPLIT][2048][64]
{
    __shared__ float ldsA[BM * KS];             // 16 KB
    __shared__ unsigned short ldsBh[OUT_D * KS];// 8 KB
    __shared__ unsigned short ldsBl[OUT_D * KS];// 8 KB

    const int t = threadIdx.x;
    const int bid = blockIdx.x;
    const int wg = (bid & 7) * 128 + (bid >> 3);
    const int mblk = wg & 31;
    const int kblk = wg >> 5;
    const int mBase = mblk * BM;
    const int kBase = kblk * KCHUNK;

    const int lane = t & 63;
    const int w = t >> 6;
    const int lr = lane & 15;
    const int g = lane >> 4;

    // per-lane swizzled source pointers (advance by KS per iter)
    const float* pA[4];
    #pragma unroll
    for (int c = 0; c < 4; ++c) {
        int s = w * 256 + c * 64 + lane;    // 16B chunk slot 0..1023
        int R = s >> 4, cc = s & 15;
        int sc = cc ^ (R & 15);
        pA[c] = conn + (size_t)(mBase + R) * KTOT + kBase + sc * 4;
    }
    const unsigned short* pBh[2];
    const unsigned short* pBl[2];
    #pragma unroll
    for (int c = 0; c < 2; ++c) {
        int s = w * 128 + c * 64 + lane;    // 16B chunk slot 0..511
        int o = s >> 3, cc = s & 7;
        int sc = cc ^ (o & 7);
        pBh[c] = wt_hi + o * KTOT + kBase + sc * 8;
        pBl[c] = wt_lo + o * KTOT + kBase + sc * 8;
    }

    f32x4 acc[4];
    #pragma unroll
    for (int nbt = 0; nbt < 4; ++nbt) acc[nbt] = 0.f;

    const int rowA = (16 * w + lr) * KS;    // f32 index of lane's A row
    #pragma unroll 1
    for (int it = 0; it < NITER; ++it) {
        const int kO = it * KS;
        #pragma unroll
        for (int c = 0; c < 4; ++c)
            gll16(pA[c] + kO, &ldsA[w * 1024 + c * 256]);
        #pragma unroll
        for (int c = 0; c < 2; ++c) {
            gll16(pBh[c] + kO, &ldsBh[(w * 128 + c * 64) * 8]);
            gll16(pBl[c] + kO, &ldsBl[(w * 128 + c * 64) * 8]);
        }
        __syncthreads();   // compiler drains vmcnt(0) here -> LDS valid

        #pragma unroll
        for (int kk = 0; kk < 2; ++kk) {
            const int cg0 = kk * 8 + g * 2;          // global chunk (even)
            float4 fa0 = *(const float4*)&ldsA[rowA + ((cg0    ) ^ lr) * 4];
            float4 fa1 = *(const float4*)&ldsA[rowA + ((cg0 + 1) ^ lr) * 4];
            short8 ah, al;
            short hh, ll;
            split2(fa0.x, hh, ll); ah[0] = hh; al[0] = ll;
            split2(fa0.y, hh, ll); ah[1] = hh; al[1] = ll;
            split2(fa0.z, hh, ll); ah[2] = hh; al[2] = ll;
            split2(fa0.w, hh, ll); ah[3] = hh; al[3] = ll;
            split2(fa1.x, hh, ll); ah[4] = hh; al[4] = ll;
            split2(fa1.y, hh, ll); ah[5] = hh; al[5] = ll;
            split2(fa1.z, hh, ll); ah[6] = hh; al[6] = ll;
            split2(fa1.w, hh, ll); ah[7] = hh; al[7] = ll;
            #pragma unroll
            for (int nbt = 0; nbt < 4; ++nbt) {
                const int o = 16 * nbt + lr;
                const int bidx = (o * 8 + ((kk * 4 + g) ^ (lr & 7))) * 8;
                short8 bh = *(const short8*)&ldsBh[bidx];
                short8 bl = *(const short8*)&ldsBl[bidx];
                acc[nbt] = __builtin_amdgcn_mfma_f32_16x16x32_bf16(al, bh, acc[nbt], 0, 0, 0);
                acc[nbt] = __builtin_amdgcn_mfma_f32_16x16x32_bf16(ah, bl, acc[nbt], 0, 0, 0);
                acc[nbt] = __builtin_amdgcn_mfma_f32_16x16x32_bf16(ah, bh, acc[nbt], 0, 0, 0);
            }
        }
        __syncthreads();
    }

    // ---- write partial tile (C/D map: col=lane&15, row=(lane>>4)*4+reg) ----
    float* dst = partials + (size_t)kblk * (NATOM * OUT_D);
    #pragma unroll
    for (int nbt = 0; nbt < 4; ++nbt) {
        #pragma unroll
        for (int rr = 0; rr < 4; ++rr) {
            const int a = mBase + 16 * w + g * 4 + rr;
            const int o = nbt * 16 + lr;
            dst[a * OUT_D + o] = acc[nbt][rr];
        }
    }
}

// ---------------------------------------------------------------------------
// K3: out = sum_s partials[s] + bond term, float4 per thread. grid 128.
// ---------------------------------------------------------------------------
__global__ __launch_bounds__(256) void reduce_kernel(
    const float* __restrict__ partials,
    const float* __restrict__ bond,     // [2048][12][2]
    const float* __restrict__ bf,       // [64][12][3]
    float* __restrict__ out)            // [2048][64]
{
    const int t4 = blockIdx.x * 256 + threadIdx.x;   // 0..32767
    const int e0 = t4 * 4;
    const int a = e0 >> 6;
    const int o0 = e0 & 63;

    float4 s = *(const float4*)&partials[e0];
    #pragma unroll
    for (int kb = 1; kb < KSPLIT; ++kb) {
        float4 p = *(const float4*)&partials[(size_t)kb * (NATOM * OUT_D) + e0];
        s.x += p.x; s.y += p.y; s.z += p.z; s.w += p.w;
    }
    const float* brow = bond + a * (FLEN * 2);       // broadcast-ish, cached
    #pragma unroll
    for (int f = 0; f < FLEN; ++f) {
        const float b0 = brow[2 * f + 0];
        const float b1 = brow[2 * f + 1];
        s.x += b0 * bf[((o0 + 0) * FLEN + f) * 3 + 1] + b1 * bf[((o0 + 0) * FLEN + f) * 3 + 2];
        s.y += b0 * bf[((o0 + 1) * FLEN + f) * 3 + 1] + b1 * bf[((o0 + 1) * FLEN + f) * 3 + 2];
        s.z += b0 * bf[((o0 + 2) * FLEN + f) * 3 + 1] + b1 * bf[((o0 + 2) * FLEN + f) * 3 + 2];
        s.w += b0 * bf[((o0 + 3) * FLEN + f) * 3 + 1] + b1 * bf[((o0 + 3) * FLEN + f) * 3 + 2];
    }
    *(float4*)&out[e0] = s;
}

extern "C" void kernel_launch(void* const* d_in, const int* in_sizes, int n_in,
                              void* d_out, int out_size, void* d_ws, size_t ws_size,
                              hipStream_t stream) {
    const float* x    = (const float*)d_in[0];   // node_property  [2048][64]
    const float* conn = (const float*)d_in[1];   // connectivity   [2048][2048][12]
    const float* bond = (const float*)d_in[2];   // bond_property  [2048][12][2]
    const float* pf   = (const float*)d_in[3];   // property_filters [64][12][64]
    const float* bf   = (const float*)d_in[4];   // bond_filters   [64][12][3]
    float* out = (float*)d_out;

    unsigned short* wt_hi = (unsigned short*)d_ws;
    unsigned short* wt_lo = wt_hi + (size_t)OUT_D * KTOT;
    float* partials = (float*)(wt_lo + (size_t)OUT_D * KTOT);
    // ws needed: 2*3,145,728 + 16,777,216 = 23,068,672 B

    compute_w_kernel<<<512, 256, 0, stream>>>(x, pf, bf, wt_hi, wt_lo);
    // MEASUREMENT: 4 idempotent K2 launches; (dur - baseline318)/3 = T(K2).
    // Same work every call (no static guards); bit-identical partials.
    main_gemm_kernel<<<1024, 256, 0, stream>>>(conn, wt_hi, wt_lo, partials);
    main_gemm_kernel<<<1024, 256, 0, stream>>>(conn, wt_hi, wt_lo, partials);
    main_gemm_kernel<<<1024, 256, 0, stream>>>(conn, wt_hi, wt_lo, partials);
    main_gemm_kernel<<<1024, 256, 0, stream>>>(conn, wt_hi, wt_lo, partials);
    reduce_kernel<<<128, 256, 0, stream>>>(partials, bond, bf, out);
}

// Round 11
// 317.468 us; speedup vs baseline: 1.3251x; 1.3251x over previous
//
#include <hip/hip_runtime.h>

// ---------------------------------------------------------------------------
// ChemConv:
//   out[a,o] = sum_{n,f} conn[a,n,f] * W[n*12+f, o] + sum_{f,c} bond[a,f,c]*bf[o,f,c+1]
//   W[n*12+f, o] = bf[o,f,0] * sum_i pf[o,f,i] * x[n,i]
//
// R9 measurement: T(K2) = 34.2 us = 224 MB traffic at >= achievable BW (floor).
// This round: eliminate the partials round-trip (33.6 MB) — bond_init writes
// the bond term into out, K2 accumulates directly via unsafeAtomicAdd (hw
// global_atomic_add_f32, device scope). K3 deleted.
// ws: [WT_hi 3MB][WT_lo 3MB] = 6,291,456 B
// ---------------------------------------------------------------------------

#define NATOM 2048
#define IN_D 64
#define OUT_D 64
#define FLEN 12
#define KTOT (NATOM * FLEN)        // 24576
#define KSPLIT 32
#define KCHUNK (KTOT / KSPLIT)     // 768
#define BM 64
#define KS 64
#define NITER (KCHUNK / KS)        // 12

typedef __attribute__((ext_vector_type(8))) short short8;   // MFMA bf16 A/B frag
typedef __attribute__((ext_vector_type(4))) float f32x4;    // MFMA C/D frag
typedef __attribute__((ext_vector_type(4))) unsigned short u16x4;

// RNE f32 -> bf16 hi/lo split: x ~= hi + lo, |x-hi-lo| <~ 2^-18 |x|
__device__ __forceinline__ void split2(float x, short& h, short& l) {
    unsigned u = __builtin_bit_cast(unsigned, x);
    unsigned r = u + 0x7fffu + ((u >> 16) & 1u);
    h = (short)(r >> 16);
    float hf = __builtin_bit_cast(float, r & 0xffff0000u);
    float res = x - hf;                       // exact (Sterbenz)
    unsigned u2 = __builtin_bit_cast(unsigned, res);
    l = (short)((u2 + 0x7fffu + ((u2 >> 16) & 1u)) >> 16);
}

// async global->LDS, 16B per lane. LDS dest must be wave-uniform base
// (HW adds lane*16); global src is per-lane.
__device__ __forceinline__ void gll16(const void* g, void* l) {
    __builtin_amdgcn_global_load_lds(
        (__attribute__((address_space(1))) void*)g,
        (__attribute__((address_space(3))) void*)l, 16, 0, 0);
}

// ---------------------------------------------------------------------------
// K0: out[a,o] = sum_f bond[a,f,0]*bf[o,f,1] + bond[a,f,1]*bf[o,f,2]
// (bond term init; K2 atomically accumulates on top). grid 128 x 256.
// ---------------------------------------------------------------------------
__global__ __launch_bounds__(256) void bond_init_kernel(
    const float* __restrict__ bond,     // [2048][12][2]
    const float* __restrict__ bf,       // [64][12][3]
    float* __restrict__ out)            // [2048][64]
{
    const int t4 = blockIdx.x * 256 + threadIdx.x;   // 0..32767
    const int e0 = t4 * 4;
    const int a = e0 >> 6;
    const int o0 = e0 & 63;

    float4 s = make_float4(0.f, 0.f, 0.f, 0.f);
    const float* brow = bond + a * (FLEN * 2);       // broadcast-ish, cached
    #pragma unroll
    for (int f = 0; f < FLEN; ++f) {
        const float b0 = brow[2 * f + 0];
        const float b1 = brow[2 * f + 1];
        s.x += b0 * bf[((o0 + 0) * FLEN + f) * 3 + 1] + b1 * bf[((o0 + 0) * FLEN + f) * 3 + 2];
        s.y += b0 * bf[((o0 + 1) * FLEN + f) * 3 + 1] + b1 * bf[((o0 + 1) * FLEN + f) * 3 + 2];
        s.z += b0 * bf[((o0 + 2) * FLEN + f) * 3 + 1] + b1 * bf[((o0 + 2) * FLEN + f) * 3 + 2];
        s.w += b0 * bf[((o0 + 3) * FLEN + f) * 3 + 1] + b1 * bf[((o0 + 3) * FLEN + f) * 3 + 2];
    }
    *(float4*)&out[e0] = s;
}

// ---------------------------------------------------------------------------
// K1: W[o][k=n*12+f] = bf[o,f,0] * sum_i pf[o,f,i]*x[n,i], stored hi/lo bf16
// o-major. grid 512 = 16 o-blocks x 32 n-blocks; 256 thr.
// ---------------------------------------------------------------------------
__global__ __launch_bounds__(256) void compute_w_kernel(
    const float* __restrict__ x,        // [2048][64]
    const float* __restrict__ pf,       // [64][12][64]
    const float* __restrict__ bf,       // [64][12][3]
    unsigned short* __restrict__ wt_hi, // [64][24576]
    unsigned short* __restrict__ wt_lo)
{
    __shared__ float x_lds[64][66];
    const int t = threadIdx.x;
    const int ob = blockIdx.x & 15;
    const int nb = blockIdx.x >> 4;

    {
        const int r = t >> 2;
        const int i0 = (t & 3) * 16;
        const float* src = x + (nb * 64 + r) * IN_D + i0;
        #pragma unroll
        for (int j = 0; j < 4; ++j) {
            float4 v = *(const float4*)(src + 4 * j);
            x_lds[r][i0 + 4 * j + 0] = v.x;
            x_lds[r][i0 + 4 * j + 1] = v.y;
            x_lds[r][i0 + 4 * j + 2] = v.z;
            x_lds[r][i0 + 4 * j + 3] = v.w;
        }
    }
    __syncthreads();

    const int l = t & 63;
    const int o = ob * 4 + (t >> 6);    // wave-uniform -> broadcast loads
    const int n = nb * 64 + l;

    float acc[FLEN];
    #pragma unroll
    for (int f = 0; f < FLEN; ++f) acc[f] = 0.f;

    for (int i = 0; i < IN_D; i += 4) {
        float x0 = x_lds[l][i + 0], x1 = x_lds[l][i + 1];
        float x2 = x_lds[l][i + 2], x3 = x_lds[l][i + 3];
        #pragma unroll
        for (int f = 0; f < FLEN; ++f) {
            float4 p = *(const float4*)(pf + (o * FLEN + f) * IN_D + i);
            acc[f] += p.x * x0 + p.y * x1 + p.z * x2 + p.w * x3;
        }
    }

    short hi[FLEN], lo[FLEN];
    #pragma unroll
    for (int f = 0; f < FLEN; ++f) {
        float wv = acc[f] * bf[(o * FLEN + f) * 3 + 0];
        split2(wv, hi[f], lo[f]);
    }
    unsigned short* dh = wt_hi + o * KTOT + n * FLEN;
    unsigned short* dl = wt_lo + o * KTOT + n * FLEN;
    #pragma unroll
    for (int q = 0; q < 3; ++q) {
        u16x4 vh = { (unsigned short)hi[4*q], (unsigned short)hi[4*q+1],
                     (unsigned short)hi[4*q+2], (unsigned short)hi[4*q+3] };
        u16x4 vl = { (unsigned short)lo[4*q], (unsigned short)lo[4*q+1],
                     (unsigned short)lo[4*q+2], (unsigned short)lo[4*q+3] };
        *(u16x4*)(dh + 4 * q) = vh;
        *(u16x4*)(dl + 4 * q) = vl;
    }
}

// ---------------------------------------------------------------------------
// K2: main GEMM. grid 1024 (XCD-swizzled) = 32 mblk x 32 kblk; 256 thr, 4 waves.
// LDS 32KB: A f32 [64 rows][16 chunks of 16B]; LDS chunk cc of row R holds
// global chunk cc^(R&15). B hi/lo ushort [64 o][8 chunks of 16B], key o&7.
// Staging via global_load_lds; hi/lo split at fragment-load time.
// Epilogue: hw f32 atomic add into out (bond term pre-written by K0).
// ---------------------------------------------------------------------------
__global__ __launch_bounds__(256, 4) void main_gemm_kernel(
    const float* __restrict__ conn,     // [2048][24576]
    const unsigned short* __restrict__ wt_hi,
    const unsigned short* __restrict__ wt_lo,
    float* __restrict__ out)            // [2048][64], accumulated atomically
{
    __shared__ float ldsA[BM * KS];             // 16 KB
    __shared__ unsigned short ldsBh[OUT_D * KS];// 8 KB
    __shared__ unsigned short ldsBl[OUT_D * KS];// 8 KB

    const int t = threadIdx.x;
    const int bid = blockIdx.x;
    const int wg = (bid & 7) * 128 + (bid >> 3);
    const int mblk = wg & 31;
    const int kblk = wg >> 5;
    const int mBase = mblk * BM;
    const int kBase = kblk * KCHUNK;

    const int lane = t & 63;
    const int w = t >> 6;
    const int lr = lane & 15;
    const int g = lane >> 4;

    // per-lane swizzled source pointers (advance by KS per iter)
    const float* pA[4];
    #pragma unroll
    for (int c = 0; c < 4; ++c) {
        int s = w * 256 + c * 64 + lane;    // 16B chunk slot 0..1023
        int R = s >> 4, cc = s & 15;
        int sc = cc ^ (R & 15);
        pA[c] = conn + (size_t)(mBase + R) * KTOT + kBase + sc * 4;
    }
    const unsigned short* pBh[2];
    const unsigned short* pBl[2];
    #pragma unroll
    for (int c = 0; c < 2; ++c) {
        int s = w * 128 + c * 64 + lane;    // 16B chunk slot 0..511
        int o = s >> 3, cc = s & 7;
        int sc = cc ^ (o & 7);
        pBh[c] = wt_hi + o * KTOT + kBase + sc * 8;
        pBl[c] = wt_lo + o * KTOT + kBase + sc * 8;
    }

    f32x4 acc[4];
    #pragma unroll
    for (int nbt = 0; nbt < 4; ++nbt) acc[nbt] = 0.f;

    const int rowA = (16 * w + lr) * KS;    // f32 index of lane's A row
    #pragma unroll 1
    for (int it = 0; it < NITER; ++it) {
        const int kO = it * KS;
        #pragma unroll
        for (int c = 0; c < 4; ++c)
            gll16(pA[c] + kO, &ldsA[w * 1024 + c * 256]);
        #pragma unroll
        for (int c = 0; c < 2; ++c) {
            gll16(pBh[c] + kO, &ldsBh[(w * 128 + c * 64) * 8]);
            gll16(pBl[c] + kO, &ldsBl[(w * 128 + c * 64) * 8]);
        }
        __syncthreads();   // compiler drains vmcnt(0) here -> LDS valid

        #pragma unroll
        for (int kk = 0; kk < 2; ++kk) {
            const int cg0 = kk * 8 + g * 2;          // global chunk (even)
            float4 fa0 = *(const float4*)&ldsA[rowA + ((cg0    ) ^ lr) * 4];
            float4 fa1 = *(const float4*)&ldsA[rowA + ((cg0 + 1) ^ lr) * 4];
            short8 ah, al;
            short hh, ll;
            split2(fa0.x, hh, ll); ah[0] = hh; al[0] = ll;
            split2(fa0.y, hh, ll); ah[1] = hh; al[1] = ll;
            split2(fa0.z, hh, ll); ah[2] = hh; al[2] = ll;
            split2(fa0.w, hh, ll); ah[3] = hh; al[3] = ll;
            split2(fa1.x, hh, ll); ah[4] = hh; al[4] = ll;
            split2(fa1.y, hh, ll); ah[5] = hh; al[5] = ll;
            split2(fa1.z, hh, ll); ah[6] = hh; al[6] = ll;
            split2(fa1.w, hh, ll); ah[7] = hh; al[7] = ll;
            #pragma unroll
            for (int nbt = 0; nbt < 4; ++nbt) {
                const int o = 16 * nbt + lr;
                const int bidx = (o * 8 + ((kk * 4 + g) ^ (lr & 7))) * 8;
                short8 bh = *(const short8*)&ldsBh[bidx];
                short8 bl = *(const short8*)&ldsBl[bidx];
                acc[nbt] = __builtin_amdgcn_mfma_f32_16x16x32_bf16(al, bh, acc[nbt], 0, 0, 0);
                acc[nbt] = __builtin_amdgcn_mfma_f32_16x16x32_bf16(ah, bl, acc[nbt], 0, 0, 0);
                acc[nbt] = __builtin_amdgcn_mfma_f32_16x16x32_bf16(ah, bh, acc[nbt], 0, 0, 0);
            }
        }
        __syncthreads();
    }

    // ---- accumulate tile into out (C/D map: col=lane&15, row=(lane>>4)*4+reg)
    // unsafeAtomicAdd -> global_atomic_add_f32 (hw, device scope).
    #pragma unroll
    for (int nbt = 0; nbt < 4; ++nbt) {
        #pragma unroll
        for (int rr = 0; rr < 4; ++rr) {
            const int a = mBase + 16 * w + g * 4 + rr;
            const int o = nbt * 16 + lr;
            unsafeAtomicAdd(&out[a * OUT_D + o], acc[nbt][rr]);
        }
    }
}

extern "C" void kernel_launch(void* const* d_in, const int* in_sizes, int n_in,
                              void* d_out, int out_size, void* d_ws, size_t ws_size,
                              hipStream_t stream) {
    const float* x    = (const float*)d_in[0];   // node_property  [2048][64]
    const float* conn = (const float*)d_in[1];   // connectivity   [2048][2048][12]
    const float* bond = (const float*)d_in[2];   // bond_property  [2048][12][2]
    const float* pf   = (const float*)d_in[3];   // property_filters [64][12][64]
    const float* bf   = (const float*)d_in[4];   // bond_filters   [64][12][3]
    float* out = (float*)d_out;

    unsigned short* wt_hi = (unsigned short*)d_ws;
    unsigned short* wt_lo = wt_hi + (size_t)OUT_D * KTOT;
    // ws needed: 2 * 3,145,728 = 6,291,456 B

    bond_init_kernel<<<128, 256, 0, stream>>>(bond, bf, out);       // out = bond term
    compute_w_kernel<<<512, 256, 0, stream>>>(x, pf, bf, wt_hi, wt_lo);
    main_gemm_kernel<<<1024, 256, 0, stream>>>(conn, wt_hi, wt_lo, out); // out += GEMM
}